// Round 12
// baseline (234.474 us; speedup 1.0000x reference)
//
#include <hip/hip_runtime.h>
#include <stdint.h>

#define EMB 1024
#define SEQ 2048
#define NB 4
#define NH 16
#define HD 64
#define NGLOB 4
#define WIN 256
#define MTOT (NB*SEQ)   // 8192
#define NQKV (3*EMB)    // 3072

// per-partial: O^T bf16 [64][32] (4096 B) + m[32] f32 + l[32] f32 (256 B)
#define PART_U16 2176   // 4352 bytes in u16 units
#define NGJOBS 4160     // global wave-jobs (segments), band-indexed
#define NLJOBS 3072     // local wave-jobs

typedef __attribute__((ext_vector_type(8))) short bf16x8;
typedef __attribute__((ext_vector_type(4))) float f32x4;
typedef __attribute__((ext_vector_type(16))) float f32x16;
typedef unsigned short u16;
typedef unsigned int u32;

#define CL2 0.18033688011112042f  // 0.125 * log2(e)

#if __has_builtin(__builtin_amdgcn_exp2f)
#define EXP2(x) __builtin_amdgcn_exp2f(x)
#else
#define EXP2(x) exp2f(x)
#endif

__device__ __forceinline__ u16 f2bf(float f) {
  u32 u = __builtin_bit_cast(u32, f);
  u += 0x7fffu + ((u >> 16) & 1u);
  return (u16)(u >> 16);
}

__device__ __forceinline__ float bf2f(u16 v) {
  u32 u = (u32)v << 16;
  return __builtin_bit_cast(float, u);
}

// truncating pack of two f32 -> dword of two bf16 (lo = a, hi = b)
__device__ __forceinline__ u32 packtrunc(float a, float b) {
  u32 ua = __builtin_bit_cast(u32, a);
  u32 ub = __builtin_bit_cast(u32, b);
  return (ua >> 16) | (ub & 0xffff0000u);
}

// NOTE: __builtin_amdgcn_permlane32_swap is BANNED this session — produced
// wrong results twice (R2, R10; identical absmax signature). shfl_xor only.

#define MFMA16(a, b, c) __builtin_amdgcn_mfma_f32_16x16x32_bf16(a, b, c, 0, 0, 0)
#define MFMA32(a, b, c) __builtin_amdgcn_mfma_f32_32x32x16_bf16(a, b, c, 0, 0, 0)
#define GLD16(g, l) __builtin_amdgcn_global_load_lds( \
    (const __attribute__((address_space(1))) void*)(g), \
    (__attribute__((address_space(3))) void*)(l), 16, 0, 0)

// ---------------- cast fp32 -> bf16 (vectorized) ----------------
__global__ void k_cast(const float* __restrict__ in, u16* __restrict__ out, int n4) {
  int i = blockIdx.x * blockDim.x + threadIdx.x;
  if (i >= n4) return;
  float4 f = ((const float4*)in)[i];
  ushort4 o;
  o.x = f2bf(f.x); o.y = f2bf(f.y); o.z = f2bf(f.z); o.w = f2bf(f.w);
  ((ushort4*)out)[i] = o;
}

// ---------------- transpose + cast: w[R][C] -> wt[C][R] bf16 ----------------
__global__ void k_transpose_cast(const float* __restrict__ w, u16* __restrict__ wt,
                                 int R, int C) {
  __shared__ float tile[32][33];
  int c0 = blockIdx.x * 32, r0 = blockIdx.y * 32;
  int tx = threadIdx.x, ty = threadIdx.y;  // 32 x 8
  #pragma unroll
  for (int j = 0; j < 32; j += 8)
    tile[ty + j][tx] = w[(size_t)(r0 + ty + j) * C + (c0 + tx)];
  __syncthreads();
  #pragma unroll
  for (int j = 0; j < 32; j += 8)
    wt[(size_t)(c0 + ty + j) * R + (r0 + tx)] = f2bf(tile[tx][ty + j]);
}

// ---------------- 256x256 bf16 MFMA GEMM (QKV projection) ----------------
// BK=32, 4-stage LDS ring (128 KiB), counted vmcnt(8) (T4), raw s_barrier,
// setprio around MFMA clusters (T5), both-sides XOR swizzle (T2, rule #21):
//   LDS row = 64 B (32 bf16); 16B-slot s at row r holds global k-slot
//   s ^ (r&3) ^ ((r>>2)&3)  -> read-side XOR is lane-constant, 2-way max.
// 512 threads = 8 waves (wm=w>>2, wn=w&3); per-wave C = 128x64.
// Epilogue scatters Q [bh][s][d], K [bh][s][d], Vf [bh][s>>4][d][s&15].
__global__ __launch_bounds__(512, 2) void k_gemm8(
    const u16* __restrict__ A, const u16* __restrict__ Bt,
    const float* __restrict__ bias,
    u16* __restrict__ Qo, u16* __restrict__ Ko, u16* __restrict__ Vt) {
  __shared__ __align__(16) char ldsb[4 * 32768];   // [buf][A 16K | B 16K]
  const int tid = threadIdx.x;
  const int w = tid >> 6, lane = tid & 63;
  const int wm = w >> 2, wn = w & 3;
  const int m0 = blockIdx.x * 256, n0 = blockIdx.y * 256;
  const int rq = lane & 15, g = lane >> 4;
  const int sxor = ((g ^ (rq & 3) ^ (rq >> 2)) << 4);   // lane-const read swz
  const int scol = ((lane & 3) ^ ((lane >> 2) & 3) ^ (lane >> 4)) * 8;
  const int srow = lane >> 2;                            // 0..15

  f32x4 acc[8][4] = {};

  const u16* Abase = A + (size_t)m0 * EMB;
  const u16* Bbase = Bt + (size_t)n0 * EMB;

  // stage one matrix-half of tile t: mat 0 = A (2 rounds), 1 = B
  auto stage = [&](int t, int mat) {
    char* dst = ldsb + (t & 3) * 32768 + mat * 16384;
    const u16* src = mat ? Bbase : Abase;
    #pragma unroll
    for (int r = 0; r < 2; ++r) {
      int row = r * 128 + w * 16 + srow;
      GLD16(src + (size_t)row * EMB + t * 32 + scol, dst + r * 8192 + w * 1024);
    }
  };

  // prologue: tiles 0,1,2 (12 loads) -> wait tile0 (keep 8 newest in flight)
  stage(0, 0); stage(0, 1); stage(1, 0); stage(1, 1); stage(2, 0); stage(2, 1);
  asm volatile("s_waitcnt vmcnt(8)" ::: "memory");
  __builtin_amdgcn_s_barrier();
  asm volatile("" ::: "memory");

  for (int t = 0; t < 32; ++t) {
    const char* Ab = ldsb + (t & 3) * 32768;
    const char* Bb = Ab + 16384;
    bf16x8 af[4], bfr[4];

    // ---- phase 0 (rows wm*128 .. +64) ----
    if (t < 29) stage(t + 3, 0);
    #pragma unroll
    for (int j = 0; j < 4; ++j) {
      int r = wm * 128 + j * 16 + rq;
      af[j] = *(const bf16x8*)(Ab + r * 64 + sxor);
      int rb = wn * 64 + j * 16 + rq;
      bfr[j] = *(const bf16x8*)(Bb + rb * 64 + sxor);
    }
    __builtin_amdgcn_s_setprio(1);
    #pragma unroll
    for (int j = 0; j < 4; ++j)
      #pragma unroll
      for (int n = 0; n < 4; ++n)
        acc[j][n] = MFMA16(af[j], bfr[n], acc[j][n]);
    __builtin_amdgcn_s_setprio(0);

    // ---- phase 1 (rows wm*128+64 .. +128) ----
    if (t < 29) stage(t + 3, 1);
    #pragma unroll
    for (int j = 0; j < 4; ++j) {
      int r = wm * 128 + (4 + j) * 16 + rq;
      af[j] = *(const bf16x8*)(Ab + r * 64 + sxor);
    }
    __builtin_amdgcn_s_setprio(1);
    #pragma unroll
    for (int j = 0; j < 4; ++j)
      #pragma unroll
      for (int n = 0; n < 4; ++n)
        acc[4 + j][n] = MFMA16(af[j], bfr[n], acc[4 + j][n]);
    __builtin_amdgcn_s_setprio(0);

    // ---- tile boundary: publish tile t+1 (counted, never drain-0 in steady) --
    if (t < 29)       asm volatile("s_waitcnt vmcnt(8)" ::: "memory");
    else if (t == 29) asm volatile("s_waitcnt vmcnt(4)" ::: "memory");
    else if (t == 30) asm volatile("s_waitcnt vmcnt(0)" ::: "memory");
    if (t < 31) {
      __builtin_amdgcn_s_barrier();
      asm volatile("" ::: "memory");
    }
  }

  // epilogue: C row = (lane>>4)*4+i, col = lane&15 (verified m89/m91)
  #pragma unroll
  for (int ni = 0; ni < 4; ++ni) {
    int col = n0 + wn * 64 + ni * 16 + rq;
    float bv = bias[col];
    int part = col >> 10;
    int hh = (col & 1023) >> 6;
    int d = col & 63;
    #pragma unroll
    for (int mi = 0; mi < 8; ++mi) {
      #pragma unroll
      for (int i = 0; i < 4; ++i) {
        int m = m0 + wm * 128 + mi * 16 + g * 4 + i;
        int b = m >> 11, s = m & 2047;
        u16 val = f2bf(acc[mi][ni][i] + bv);
        size_t bh = (size_t)(b * NH + hh);
        if (part == 0)      Qo[(bh * SEQ + s) * HD + d] = val;
        else if (part == 1) Ko[(bh * SEQ + s) * HD + d] = val;
        else                Vt[((bh * 128 + (s >> 4)) * 64 + d) * 16 + (s & 15)] = val;
      }
    }
  }
}

// ---------------- 128x128 bf16 MFMA GEMM (out projection) ----------------
__global__ __launch_bounds__(256, 2) void k_gemm_out(
    const u16* __restrict__ A, const u16* __restrict__ Bt,
    const float* __restrict__ bias, float* __restrict__ outp) {
  __shared__ __align__(16) u16 ldsA[128 * 64];
  __shared__ __align__(16) u16 ldsB[128 * 64];
  const int tid = threadIdx.x;
  const int w = tid >> 6, lane = tid & 63;
  const int wm = w >> 1, wn = w & 1;
  const int m0 = blockIdx.x * 128, n0 = blockIdx.y * 128;
  const int rq = lane & 15, g = lane >> 4;

  const int srow = lane >> 3;
  const int scol = ((lane & 7) ^ srow) << 3;

  f32x4 acc[4][4] = {};
  char* ldsAb = (char*)ldsA;
  char* ldsBb = (char*)ldsB;

  for (int k0 = 0; k0 < EMB; k0 += 64) {
    #pragma unroll
    for (int it = 0; it < 4; ++it) {
      int t = w * 4 + it;
      int row = t * 8 + srow;
      GLD16(A + (size_t)(m0 + row) * EMB + k0 + scol, ldsAb + t * 1024);
      GLD16(Bt + (size_t)(n0 + row) * EMB + k0 + scol, ldsBb + t * 1024);
    }
    __syncthreads();
    #pragma unroll
    for (int ks = 0; ks < 2; ++ks) {
      bf16x8 af[4], bfr[4];
      #pragma unroll
      for (int i = 0; i < 4; ++i) {
        int rowA = wm * 64 + i * 16 + rq;
        int off = (ks * 64 + (g << 4)) ^ ((rowA & 7) << 4);
        af[i] = *(const bf16x8*)(ldsAb + rowA * 128 + off);
        int rowB = wn * 64 + i * 16 + rq;
        int offb = (ks * 64 + (g << 4)) ^ ((rowB & 7) << 4);
        bfr[i] = *(const bf16x8*)(ldsBb + rowB * 128 + offb);
      }
      #pragma unroll
      for (int mi = 0; mi < 4; ++mi)
        #pragma unroll
        for (int ni = 0; ni < 4; ++ni)
          acc[mi][ni] = MFMA16(af[mi], bfr[ni], acc[mi][ni]);
    }
    __syncthreads();
  }

  #pragma unroll
  for (int ni = 0; ni < 4; ++ni) {
    int col = n0 + wn * 64 + ni * 16 + rq;
    float bv = bias[col];
    #pragma unroll
    for (int mi = 0; mi < 4; ++mi)
      #pragma unroll
      for (int i = 0; i < 4; ++i) {
        int m = m0 + wm * 64 + mi * 16 + g * 4 + i;
        outp[(size_t)m * EMB + col] = acc[mi][ni][i] + bv;
      }
  }
}

// ---------------- flash attention pass 1: uniform wave-jobs (<=9 chunks) ----
__global__ __launch_bounds__(256, 4) void k_attn(
    const u16* __restrict__ Q, const u16* __restrict__ K,
    const u16* __restrict__ Vt, u16* __restrict__ ctx,
    u16* __restrict__ part) {
  const int w = threadIdx.x >> 6, lane = threadIdx.x & 63;
  const int l31 = lane & 31;
  const int hi = lane >> 5;
  const bool hib = hi != 0;
  const int hi8 = hi * 8, hi4 = hi * 4;

  const int j = blockIdx.x * 4 + w;         // wave-job id
  const bool isglob = j < NGJOBS;

  int bh, qt, cstart, clen;
  if (isglob) {
    int rem = j, b = 0;
    while (b < 7 && rem >= 144 * (b + 1)) { rem -= 144 * (b + 1); ++b; }
    int nseg = b + 1;
    int qoff = (rem >> 4) / nseg;
    int r2 = rem - qoff * 16 * nseg;
    int seg = r2 >> 4, bg = r2 & 15;
    qt = 9 * b + qoff;
    bh = (bg >> 2) * 16 + (bg & 3);
    int L = qt + 1;
    int base = L / nseg, rm = L - base * nseg;
    clen = base + (seg < rm ? 1 : 0);
    cstart = seg * base + (seg < rm ? seg : rm);
  } else {
    int lidx = j - NGJOBS;                   // 0..3071
    int bl = lidx >> 6;
    bh = (bl / 12) * 16 + 4 + (bl % 12);
    qt = lidx & 63;
    int qb_ = qt * 32;
    int klo = (qb_ > WIN) ? qb_ - WIN : 0;
    cstart = klo >> 5;
    clen = qt + 1 - cstart;
  }

  const int qb = qt * 32;
  const int h = bh & 15;
  const int b_ = bh >> 4;
  const bool isloc = !isglob;

  const u16* Qp = Q + (size_t)bh * SEQ * HD;
  const u16* Kp = K + (size_t)bh * SEQ * HD;
  const u16* Vp = Vt + (size_t)bh * SEQ * HD;   // 16-key-blocked layout

  const int q = qb + l31;
  const float NINF = -__builtin_inff();

  bf16x8 qf[4];
  #pragma unroll
  for (int jj = 0; jj < 4; ++jj)
    qf[jj] = *(const bf16x8*)(Qp + (size_t)q * HD + jj * 16 + hi8);

  f32x16 oacc[2] = {};
  float m = NINF;
  float l = 0.f;

  int kc = cstart * 32;
  #pragma unroll 2
  for (int it = 0; it < clen; ++it, kc += 32) {
    bf16x8 kf0, kf1, kf2, kf3, vf[2][2];
    {
      const u16* Kr = Kp + (size_t)(kc + l31) * HD + hi8;
      kf0 = *(const bf16x8*)(Kr);
      kf1 = *(const bf16x8*)(Kr + 16);
      kf2 = *(const bf16x8*)(Kr + 32);
      kf3 = *(const bf16x8*)(Kr + 48);
      const u16* Vb = Vp + (size_t)(kc >> 4) * 1024 + hi8;
      #pragma unroll
      for (int dt = 0; dt < 2; ++dt)
        #pragma unroll
        for (int sl = 0; sl < 2; ++sl)
          vf[dt][sl] = *(const bf16x8*)(Vb + (sl * 64 + dt * 32 + l31) * 16);
    }

    f32x16 s0 = {}, s1 = {};
    s0 = MFMA32(kf0, qf[0], s0);
    s1 = MFMA32(kf2, qf[2], s1);
    s0 = MFMA32(kf1, qf[1], s0);
    s1 = MFMA32(kf3, qf[3], s1);

    const bool needs_mask = (kc == qb) || (isloc && (qb - kc > 225));
    float p[16];
    float cmax = NINF;
    if (needs_mask) {
      #pragma unroll
      for (int r = 0; r < 16; ++r) {
        int key = kc + hi4 + (r & 3) + 8 * (r >> 2);
        float v = s0[r] + s1[r];
        bool bad = (key > q) || (isloc && (q - key > WIN));
        p[r] = bad ? NINF : v;
        cmax = fmaxf(cmax, p[r]);
      }
    } else {
      #pragma unroll
      for (int r = 0; r < 16; ++r) {
        p[r] = s0[r] + s1[r];
        cmax = fmaxf(cmax, p[r]);
      }
    }
    cmax = fmaxf(cmax, __shfl_xor(cmax, 32));

    float muC;
    if (__any(cmax > m + 64.f)) {
      float mn = fmaxf(m, cmax);
      muC = (mn == NINF) ? 0.f : mn * CL2;
      float oldC = (m == NINF) ? muC : m * CL2;
      float f = EXP2(oldC - muC);
      m = mn;
      l *= f;
      #pragma unroll
      for (int dt = 0; dt < 2; ++dt)
        #pragma unroll
        for (int r = 0; r < 16; ++r)
          oacc[dt][r] *= f;
    } else {
      muC = (m == NINF) ? 0.f : m * CL2;
    }

    float psum = 0.f;
    #pragma unroll
    for (int r = 0; r < 16; ++r) {
      float e = EXP2(__builtin_fmaf(p[r], CL2, -muC));
      p[r] = e;
      psum += e;
    }
    psum += __shfl_xor(psum, 32);
    l += psum;

    union { u32 u[4]; bf16x8 v; } pbf[2];
    #pragma unroll
    for (int sl = 0; sl < 2; ++sl) {
      int s8 = sl * 8;
      u32 X0 = packtrunc(p[s8 + 0], p[s8 + 1]);
      u32 X1 = packtrunc(p[s8 + 2], p[s8 + 3]);
      u32 X2 = packtrunc(p[s8 + 4], p[s8 + 5]);
      u32 X3 = packtrunc(p[s8 + 6], p[s8 + 7]);
      u32 oX0 = (u32)__shfl_xor((int)X0, 32);
      u32 oX1 = (u32)__shfl_xor((int)X1, 32);
      u32 oX2 = (u32)__shfl_xor((int)X2, 32);
      u32 oX3 = (u32)__shfl_xor((int)X3, 32);
      pbf[sl].u[0] = hib ? oX2 : X0;
      pbf[sl].u[1] = hib ? oX3 : X1;
      pbf[sl].u[2] = hib ? X2 : oX0;
      pbf[sl].u[3] = hib ? X3 : oX1;
    }

    #pragma unroll
    for (int dt = 0; dt < 2; ++dt)
      #pragma unroll
      for (int sl = 0; sl < 2; ++sl)
        oacc[dt] = MFMA32(vf[dt][sl], pbf[sl].v, oacc[dt]);
  }

  if (isglob) {
    u16* PB = part + (size_t)j * PART_U16;
    #pragma unroll
    for (int dt = 0; dt < 2; ++dt)
      #pragma unroll
      for (int r = 0; r < 16; ++r) {
        int d = dt * 32 + hi4 + (r & 3) + 8 * (r >> 2);
        PB[d * 32 + l31] = f2bf(oacc[dt][r]);
      }
    float* PF = (float*)(PB + 2048);
    if (hi == 0) { PF[l31] = m; PF[32 + l31] = l; }
  } else {
    float linv = 1.f / l;
    #pragma unroll
    for (int dt = 0; dt < 2; ++dt) {
      #pragma unroll
      for (int r = 0; r < 16; ++r) {
        int d = dt * 32 + hi4 + (r & 3) + 8 * (r >> 2);
        int e = h * HD + d;
        ctx[(size_t)(b_ * SEQ + q) * EMB + e] = f2bf(oacc[dt][r] * linv);
      }
    }
  }
}

// ---------------- flash attention pass 2: merge nseg partials per task ----
__global__ __launch_bounds__(256, 4) void k_merge(
    const u16* __restrict__ part, u16* __restrict__ ctx) {
  const int t = blockIdx.x;                  // 0..1023: (qt, bg)
  const int bg = t & 15;
  const int qt = t >> 4;
  const int b = qt / 9;                      // band, 0..7
  const int nseg = b + 1;
  const int jbase = 72 * b * (b + 1) + (qt - 9 * b) * 16 * nseg + bg;
  const int bh = (bg >> 2) * 16 + (bg & 3);
  const int qb = qt * 32;
  const int h = bh & 15;
  const int bb = bh >> 4;

  const int tid = threadIdx.x;
  const int dd = tid & 63;
  const int qg = tid >> 6;                   // 0..3
  #pragma unroll
  for (int i = 0; i < 8; ++i) {
    int qq = qg * 8 + i;
    float M = -__builtin_inff();
    for (int s = 0; s < nseg; ++s) {
      const float* F = (const float*)(part + (size_t)(jbase + s * 16) * PART_U16 + 2048);
      M = fmaxf(M, F[qq]);
    }
    float L = 0.f, val = 0.f;
    for (int s = 0; s < nseg; ++s) {
      const u16* P = part + (size_t)(jbase + s * 16) * PART_U16;
      const float* F = (const float*)(P + 2048);
      float wgt = EXP2((F[qq] - M) * CL2);
      L += wgt * F[32 + qq];
      val += wgt * bf2f(P[dd * 32 + qq]);
    }
    int s_ = qb + qq;
    ctx[(size_t)(bb * SEQ + s_) * EMB + h * HD + dd] = f2bf(val / L);
  }
}

extern "C" void kernel_launch(void* const* d_in, const int* in_sizes, int n_in,
                              void* d_out, int out_size, void* d_ws, size_t ws_size,
                              hipStream_t stream) {
  const float* x     = (const float*)d_in[0];
  const float* w_qkv = (const float*)d_in[1];
  const float* b_qkv = (const float*)d_in[2];
  const float* w_out = (const float*)d_in[3];
  const float* b_out = (const float*)d_in[4];
  float* out = (float*)d_out;

  char* ws = (char*)d_ws;
  u16* xb    = (u16*)(ws);                   // 16 MiB (dead after k_gemm8)
  u16* wqkvT = (u16*)(ws + (16ull << 20));   // 6 MiB  (dead after k_gemm8)
  u16* woutT = (u16*)(ws + (22ull << 20));   // 2 MiB
  u16* Qb    = (u16*)(ws + (24ull << 20));   // 16 MiB
  u16* Kb    = (u16*)(ws + (40ull << 20));   // 16 MiB
  u16* Vt    = (u16*)(ws + (56ull << 20));   // 16 MiB (16-key-blocked layout)
  u16* ctx   = (u16*)(ws + (72ull << 20));   // 16 MiB
  u16* part  = xb;                           // 18.1 MiB partials (xb+wqkvT)

  k_cast<<<(MTOT * EMB / 4) / 256, 256, 0, stream>>>(x, xb, MTOT * EMB / 4);
  dim3 tb(32, 8);
  k_transpose_cast<<<dim3(NQKV / 32, EMB / 32), tb, 0, stream>>>(w_qkv, wqkvT, EMB, NQKV);
  k_transpose_cast<<<dim3(EMB / 32, EMB / 32), tb, 0, stream>>>(w_out, woutT, EMB, EMB);

  k_gemm8<<<dim3(MTOT / 256, NQKV / 256), 512, 0, stream>>>(
      xb, wqkvT, b_qkv, Qb, Kb, Vt);

  k_attn<<<dim3((NGJOBS + NLJOBS) / 4), 256, 0, stream>>>(Qb, Kb, Vt, ctx, part);
  k_merge<<<dim3(1024), 256, 0, stream>>>(part, ctx);

  k_gemm_out<<<dim3(MTOT / 128, EMB / 128), 256, 0, stream>>>(
      ctx, woutT, b_out, out);
}

// Round 13
// 234.434 us; speedup vs baseline: 1.0002x; 1.0002x over previous
//
#include <hip/hip_runtime.h>
#include <stdint.h>

#define EMB 1024
#define SEQ 2048
#define NB 4
#define NH 16
#define HD 64
#define NGLOB 4
#define WIN 256
#define MTOT (NB*SEQ)   // 8192
#define NQKV (3*EMB)    // 3072

// per-partial: O^T bf16 [64][32] (4096 B) + m[32] f32 + l[32] f32 (256 B)
#define PART_U16 2176   // 4352 bytes in u16 units
#define NGJOBS 4160     // global wave-jobs (segments), band-indexed
#define NLJOBS 3072     // local wave-jobs

typedef __attribute__((ext_vector_type(8))) short bf16x8;
typedef __attribute__((ext_vector_type(4))) float f32x4;
typedef __attribute__((ext_vector_type(16))) float f32x16;
typedef unsigned short u16;
typedef unsigned int u32;

#define CL2 0.18033688011112042f  // 0.125 * log2(e)

#if __has_builtin(__builtin_amdgcn_exp2f)
#define EXP2(x) __builtin_amdgcn_exp2f(x)
#else
#define EXP2(x) exp2f(x)
#endif

__device__ __forceinline__ u16 f2bf(float f) {
  u32 u = __builtin_bit_cast(u32, f);
  u += 0x7fffu + ((u >> 16) & 1u);
  return (u16)(u >> 16);
}

__device__ __forceinline__ float bf2f(u16 v) {
  u32 u = (u32)v << 16;
  return __builtin_bit_cast(float, u);
}

// truncating pack of two f32 -> dword of two bf16 (lo = a, hi = b)
__device__ __forceinline__ u32 packtrunc(float a, float b) {
  u32 ua = __builtin_bit_cast(u32, a);
  u32 ub = __builtin_bit_cast(u32, b);
  return (ua >> 16) | (ub & 0xffff0000u);
}

// NOTE: __builtin_amdgcn_permlane32_swap is BANNED this session — produced
// wrong results twice (R2, R10; identical absmax signature). shfl_xor only.

#define MFMA16(a, b, c) __builtin_amdgcn_mfma_f32_16x16x32_bf16(a, b, c, 0, 0, 0)
#define MFMA32(a, b, c) __builtin_amdgcn_mfma_f32_32x32x16_bf16(a, b, c, 0, 0, 0)
#define GLD16(g, l) __builtin_amdgcn_global_load_lds( \
    (const __attribute__((address_space(1))) void*)(g), \
    (__attribute__((address_space(3))) void*)(l), 16, 0, 0)

// ---------------- cast fp32 -> bf16 (vectorized) ----------------
__global__ void k_cast(const float* __restrict__ in, u16* __restrict__ out, int n4) {
  int i = blockIdx.x * blockDim.x + threadIdx.x;
  if (i >= n4) return;
  float4 f = ((const float4*)in)[i];
  ushort4 o;
  o.x = f2bf(f.x); o.y = f2bf(f.y); o.z = f2bf(f.z); o.w = f2bf(f.w);
  ((ushort4*)out)[i] = o;
}

// ---------------- transpose + cast: w[R][C] -> wt[C][R] bf16 ----------------
__global__ void k_transpose_cast(const float* __restrict__ w, u16* __restrict__ wt,
                                 int R, int C) {
  __shared__ float tile[32][33];
  int c0 = blockIdx.x * 32, r0 = blockIdx.y * 32;
  int tx = threadIdx.x, ty = threadIdx.y;  // 32 x 8
  #pragma unroll
  for (int j = 0; j < 32; j += 8)
    tile[ty + j][tx] = w[(size_t)(r0 + ty + j) * C + (c0 + tx)];
  __syncthreads();
  #pragma unroll
  for (int j = 0; j < 32; j += 8)
    wt[(size_t)(c0 + ty + j) * R + (r0 + tx)] = f2bf(tile[tx][ty + j]);
}

// ---------------- 128x128 bf16 MFMA GEMM, K=1024, B given transposed -------
// 1D grid with bijective XCD swizzle (T1): NWG = NX*NY, NWG % 8 == 0.
// EPI==0 epilogue: Q [bh][s][d], K [bh][s][d], Vf [bh][s>>4][d][s&15].
// EPI==1 epilogue: fp32 out + bias.
template <int EPI, int NX, int NY>
__global__ __launch_bounds__(256, 2) void k_gemm(
    const u16* __restrict__ A, const u16* __restrict__ Bt,
    const float* __restrict__ bias,
    u16* __restrict__ Qo, u16* __restrict__ Ko, u16* __restrict__ Vt,
    float* __restrict__ outp) {
  __shared__ __align__(16) u16 ldsA[128 * 64];
  __shared__ __align__(16) u16 ldsB[128 * 64];
  const int tid = threadIdx.x;
  const int w = tid >> 6, lane = tid & 63;
  const int wm = w >> 1, wn = w & 1;
  constexpr int CPX = (NX * NY) / 8;
  const int gid = blockIdx.x;
  const int wg = (gid & 7) * CPX + (gid >> 3);
  const int m0 = (wg % NX) * 128;
  const int n0 = (wg / NX) * 128;
  const int rq = lane & 15, g = lane >> 4;

  const int srow = lane >> 3;
  const int scol = ((lane & 7) ^ srow) << 3;

  f32x4 acc[4][4] = {};
  char* ldsAb = (char*)ldsA;
  char* ldsBb = (char*)ldsB;

  for (int k0 = 0; k0 < EMB; k0 += 64) {
    #pragma unroll
    for (int it = 0; it < 4; ++it) {
      int t = w * 4 + it;
      int row = t * 8 + srow;
      GLD16(A + (size_t)(m0 + row) * EMB + k0 + scol, ldsAb + t * 1024);
      GLD16(Bt + (size_t)(n0 + row) * EMB + k0 + scol, ldsBb + t * 1024);
    }
    __syncthreads();
    #pragma unroll
    for (int ks = 0; ks < 2; ++ks) {
      bf16x8 af[4], bfr[4];
      #pragma unroll
      for (int i = 0; i < 4; ++i) {
        int rowA = wm * 64 + i * 16 + rq;
        int off = (ks * 64 + (g << 4)) ^ ((rowA & 7) << 4);
        af[i] = *(const bf16x8*)(ldsAb + rowA * 128 + off);
        int rowB = wn * 64 + i * 16 + rq;
        int offb = (ks * 64 + (g << 4)) ^ ((rowB & 7) << 4);
        bfr[i] = *(const bf16x8*)(ldsBb + rowB * 128 + offb);
      }
      #pragma unroll
      for (int mi = 0; mi < 4; ++mi)
        #pragma unroll
        for (int ni = 0; ni < 4; ++ni)
          acc[mi][ni] = MFMA16(af[mi], bfr[ni], acc[mi][ni]);
    }
    __syncthreads();
  }

  #pragma unroll
  for (int ni = 0; ni < 4; ++ni) {
    int col = n0 + wn * 64 + ni * 16 + rq;
    float bv = bias[col];
    if (EPI == 0) {
      int part = col >> 10;
      int hh = (col & 1023) >> 6;
      int d = col & 63;
      #pragma unroll
      for (int mi = 0; mi < 4; ++mi) {
        #pragma unroll
        for (int i = 0; i < 4; ++i) {
          int m = m0 + wm * 64 + mi * 16 + g * 4 + i;
          int b = m >> 11, s = m & 2047;
          u16 val = f2bf(acc[mi][ni][i] + bv);
          size_t bh = (size_t)(b * NH + hh);
          if (part == 0)      Qo[(bh * SEQ + s) * HD + d] = val;
          else if (part == 1) Ko[(bh * SEQ + s) * HD + d] = val;
          else                Vt[((bh * 128 + (s >> 4)) * 64 + d) * 16 + (s & 15)] = val;
        }
      }
    } else {
      #pragma unroll
      for (int mi = 0; mi < 4; ++mi)
        #pragma unroll
        for (int i = 0; i < 4; ++i) {
          int m = m0 + wm * 64 + mi * 16 + g * 4 + i;
          outp[(size_t)m * EMB + col] = acc[mi][ni][i] + bv;
        }
    }
  }
}

// ---------------- flash attention pass 1: uniform wave-jobs (<=9 chunks) ----
// job j < NGJOBS: global-head SEGMENT (band-indexed). band>0 -> partial to
//   scratch; band==0 (nseg==1, full range) -> direct ctx write.
// job j >= NGJOBS: local-head task (<=9 chunks), direct ctx write.
__global__ __launch_bounds__(256, 4) void k_attn(
    const u16* __restrict__ Q, const u16* __restrict__ K,
    const u16* __restrict__ Vt, u16* __restrict__ ctx,
    u16* __restrict__ part) {
  const int w = threadIdx.x >> 6, lane = threadIdx.x & 63;
  const int l31 = lane & 31;
  const int hi = lane >> 5;
  const bool hib = hi != 0;
  const int hi8 = hi * 8, hi4 = hi * 4;

  const int j = blockIdx.x * 4 + w;         // wave-job id
  const bool isglob = j < NGJOBS;

  int bh, qt, cstart, clen, band = 0;
  if (isglob) {
    int rem = j, b = 0;
    while (b < 7 && rem >= 144 * (b + 1)) { rem -= 144 * (b + 1); ++b; }
    band = b;
    int nseg = b + 1;
    int qoff = (rem >> 4) / nseg;
    int r2 = rem - qoff * 16 * nseg;
    int seg = r2 >> 4, bg = r2 & 15;
    qt = 9 * b + qoff;
    bh = (bg >> 2) * 16 + (bg & 3);
    int L = qt + 1;
    int base = L / nseg, rm = L - base * nseg;
    clen = base + (seg < rm ? 1 : 0);
    cstart = seg * base + (seg < rm ? seg : rm);
  } else {
    int lidx = j - NGJOBS;                   // 0..3071
    int bl = lidx >> 6;
    bh = (bl / 12) * 16 + 4 + (bl % 12);
    qt = lidx & 63;
    int qb_ = qt * 32;
    int klo = (qb_ > WIN) ? qb_ - WIN : 0;
    cstart = klo >> 5;
    clen = qt + 1 - cstart;
  }

  const int qb = qt * 32;
  const int h = bh & 15;
  const int b_ = bh >> 4;
  const bool isloc = !isglob;

  const u16* Qp = Q + (size_t)bh * SEQ * HD;
  const u16* Kp = K + (size_t)bh * SEQ * HD;
  const u16* Vp = Vt + (size_t)bh * SEQ * HD;   // 16-key-blocked layout

  const int q = qb + l31;
  const float NINF = -__builtin_inff();

  bf16x8 qf[4];
  #pragma unroll
  for (int jj = 0; jj < 4; ++jj)
    qf[jj] = *(const bf16x8*)(Qp + (size_t)q * HD + jj * 16 + hi8);

  f32x16 oacc[2] = {};
  float m = NINF;
  float l = 0.f;

  int kc = cstart * 32;
  #pragma unroll 2
  for (int it = 0; it < clen; ++it, kc += 32) {
    bf16x8 kf0, kf1, kf2, kf3, vf[2][2];
    {
      const u16* Kr = Kp + (size_t)(kc + l31) * HD + hi8;
      kf0 = *(const bf16x8*)(Kr);
      kf1 = *(const bf16x8*)(Kr + 16);
      kf2 = *(const bf16x8*)(Kr + 32);
      kf3 = *(const bf16x8*)(Kr + 48);
      const u16* Vb = Vp + (size_t)(kc >> 4) * 1024 + hi8;
      #pragma unroll
      for (int dt = 0; dt < 2; ++dt)
        #pragma unroll
        for (int sl = 0; sl < 2; ++sl)
          vf[dt][sl] = *(const bf16x8*)(Vb + (sl * 64 + dt * 32 + l31) * 16);
    }

    f32x16 s0 = {}, s1 = {};
    s0 = MFMA32(kf0, qf[0], s0);
    s1 = MFMA32(kf2, qf[2], s1);
    s0 = MFMA32(kf1, qf[1], s0);
    s1 = MFMA32(kf3, qf[3], s1);

    const bool needs_mask = (kc == qb) || (isloc && (qb - kc > 225));
    float p[16];
    float cmax = NINF;
    if (needs_mask) {
      #pragma unroll
      for (int r = 0; r < 16; ++r) {
        int key = kc + hi4 + (r & 3) + 8 * (r >> 2);
        float v = s0[r] + s1[r];
        bool bad = (key > q) || (isloc && (q - key > WIN));
        p[r] = bad ? NINF : v;
        cmax = fmaxf(cmax, p[r]);
      }
    } else {
      #pragma unroll
      for (int r = 0; r < 16; ++r) {
        p[r] = s0[r] + s1[r];
        cmax = fmaxf(cmax, p[r]);
      }
    }
    cmax = fmaxf(cmax, __shfl_xor(cmax, 32));

    float muC;
    if (__any(cmax > m + 64.f)) {
      float mn = fmaxf(m, cmax);
      muC = (mn == NINF) ? 0.f : mn * CL2;
      float oldC = (m == NINF) ? muC : m * CL2;
      float f = EXP2(oldC - muC);
      m = mn;
      l *= f;
      #pragma unroll
      for (int dt = 0; dt < 2; ++dt)
        #pragma unroll
        for (int r = 0; r < 16; ++r)
          oacc[dt][r] *= f;
    } else {
      muC = (m == NINF) ? 0.f : m * CL2;
    }

    float psum = 0.f;
    #pragma unroll
    for (int r = 0; r < 16; ++r) {
      float e = EXP2(__builtin_fmaf(p[r], CL2, -muC));
      p[r] = e;
      psum += e;
    }
    psum += __shfl_xor(psum, 32);
    l += psum;

    union { u32 u[4]; bf16x8 v; } pbf[2];
    #pragma unroll
    for (int sl = 0; sl < 2; ++sl) {
      int s8 = sl * 8;
      u32 X0 = packtrunc(p[s8 + 0], p[s8 + 1]);
      u32 X1 = packtrunc(p[s8 + 2], p[s8 + 3]);
      u32 X2 = packtrunc(p[s8 + 4], p[s8 + 5]);
      u32 X3 = packtrunc(p[s8 + 6], p[s8 + 7]);
      u32 oX0 = (u32)__shfl_xor((int)X0, 32);
      u32 oX1 = (u32)__shfl_xor((int)X1, 32);
      u32 oX2 = (u32)__shfl_xor((int)X2, 32);
      u32 oX3 = (u32)__shfl_xor((int)X3, 32);
      pbf[sl].u[0] = hib ? oX2 : X0;
      pbf[sl].u[1] = hib ? oX3 : X1;
      pbf[sl].u[2] = hib ? X2 : oX0;
      pbf[sl].u[3] = hib ? X3 : oX1;
    }

    #pragma unroll
    for (int dt = 0; dt < 2; ++dt)
      #pragma unroll
      for (int sl = 0; sl < 2; ++sl)
        oacc[dt] = MFMA32(vf[dt][sl], pbf[sl].v, oacc[dt]);
  }

  if (isglob && band != 0) {
    // store wave-private partial: O^T bf16 [64][32] + m,l f32 at slot j
    u16* PB = part + (size_t)j * PART_U16;
    #pragma unroll
    for (int dt = 0; dt < 2; ++dt)
      #pragma unroll
      for (int r = 0; r < 16; ++r) {
        int d = dt * 32 + hi4 + (r & 3) + 8 * (r >> 2);
        PB[d * 32 + l31] = f2bf(oacc[dt][r]);
      }
    float* PF = (float*)(PB + 2048);
    if (hi == 0) { PF[l31] = m; PF[32 + l31] = l; }
  } else {
    // direct write (locals, and band-0 globals which cover the full range)
    float linv = 1.f / l;
    #pragma unroll
    for (int dt = 0; dt < 2; ++dt) {
      #pragma unroll
      for (int r = 0; r < 16; ++r) {
        int d = dt * 32 + hi4 + (r & 3) + 8 * (r >> 2);
        int e = h * HD + d;
        ctx[(size_t)(b_ * SEQ + q) * EMB + e] = f2bf(oacc[dt][r] * linv);
      }
    }
  }
}

// ---------------- flash attention pass 2: merge nseg partials per task ----
// LDS-staged: O-partials copied coalesced, read transposed via padded rows.
__global__ __launch_bounds__(256, 4) void k_merge(
    const u16* __restrict__ part, u16* __restrict__ ctx) {
  const int t = blockIdx.x;                  // 0..1023: (qt, bg)
  const int bg = t & 15;
  const int qt = t >> 4;
  const int band = qt / 9;                   // 0..7
  const int nseg = band + 1;
  if (nseg == 1) return;                     // pass 1 wrote ctx directly
  const int jbase = 72 * band * (band + 1) + (qt - 9 * band) * 16 * nseg + bg;
  const int bh = (bg >> 2) * 16 + (bg & 3);
  const int qb = qt * 32;
  const int h = bh & 15;
  const int bb = bh >> 4;

  __shared__ u16 ob[64][34];                 // padded: bank = dd*17+q/2 (2-way)
  __shared__ float fml[8][64];               // [seg][m[32] | l[32]]

  const int tid = threadIdx.x;
  for (int e = tid; e < nseg * 64; e += 256) {
    int s = e >> 6, k = e & 63;
    fml[s][k] = ((const float*)(part + (size_t)(jbase + s * 16) * PART_U16 + 2048))[k];
  }
  __syncthreads();

  const int dd = tid & 63;
  const int qg = tid >> 6;                   // 0..3 (wave id -> qq uniform/wave)
  float M[8], Lsum[8], val[8];
  #pragma unroll
  for (int i = 0; i < 8; ++i) {
    int qq = qg * 8 + i;
    float mx = fml[0][qq];
    for (int s = 1; s < nseg; ++s) mx = fmaxf(mx, fml[s][qq]);
    M[i] = mx; Lsum[i] = 0.f; val[i] = 0.f;
  }

  for (int s = 0; s < nseg; ++s) {
    __syncthreads();
    const u32* src = (const u32*)(part + (size_t)(jbase + s * 16) * PART_U16);
    #pragma unroll
    for (int c = 0; c < 4; ++c) {
      int wd = tid * 4 + c;                  // 0..1023 words of the 4KB O-part
      *(u32*)&ob[wd >> 4][(wd & 15) * 2] = src[wd];
    }
    __syncthreads();
    #pragma unroll
    for (int i = 0; i < 8; ++i) {
      int qq = qg * 8 + i;
      float wgt = EXP2((fml[s][qq] - M[i]) * CL2);
      Lsum[i] += wgt * fml[s][32 + qq];
      val[i] += wgt * bf2f(ob[dd][qq]);
    }
  }

  #pragma unroll
  for (int i = 0; i < 8; ++i) {
    int qq = qg * 8 + i;
    ctx[(size_t)(bb * SEQ + (qb + qq)) * EMB + h * HD + dd] = f2bf(val[i] / Lsum[i]);
  }
}

extern "C" void kernel_launch(void* const* d_in, const int* in_sizes, int n_in,
                              void* d_out, int out_size, void* d_ws, size_t ws_size,
                              hipStream_t stream) {
  const float* x     = (const float*)d_in[0];
  const float* w_qkv = (const float*)d_in[1];
  const float* b_qkv = (const float*)d_in[2];
  const float* w_out = (const float*)d_in[3];
  const float* b_out = (const float*)d_in[4];
  float* out = (float*)d_out;

  char* ws = (char*)d_ws;
  u16* xb    = (u16*)(ws);                   // 16 MiB (dead after k_gemm<0>)
  u16* wqkvT = (u16*)(ws + (16ull << 20));   // 6 MiB  (dead after k_gemm<0>)
  u16* woutT = (u16*)(ws + (22ull << 20));   // 2 MiB
  u16* Qb    = (u16*)(ws + (24ull << 20));   // 16 MiB
  u16* Kb    = (u16*)(ws + (40ull << 20));   // 16 MiB
  u16* Vt    = (u16*)(ws + (56ull << 20));   // 16 MiB (16-key-blocked layout)
  u16* ctx   = (u16*)(ws + (72ull << 20));   // 16 MiB
  u16* part  = xb;                           // 18.1 MiB partials (xb+wqkvT)

  k_cast<<<(MTOT * EMB / 4) / 256, 256, 0, stream>>>(x, xb, MTOT * EMB / 4);
  dim3 tb(32, 8);
  k_transpose_cast<<<dim3(NQKV / 32, EMB / 32), tb, 0, stream>>>(w_qkv, wqkvT, EMB, NQKV);
  k_transpose_cast<<<dim3(EMB / 32, EMB / 32), tb, 0, stream>>>(w_out, woutT, EMB, EMB);

  k_gemm<0, 64, 24><<<dim3(64 * 24), 256, 0, stream>>>(
      xb, wqkvT, b_qkv, Qb, Kb, Vt, nullptr);

  k_attn<<<dim3((NGJOBS + NLJOBS) / 4), 256, 0, stream>>>(Qb, Kb, Vt, ctx, part);
  k_merge<<<dim3(1024), 256, 0, stream>>>(part, ctx);

  k_gemm<1, 64, 8><<<dim3(64 * 8), 256, 0, stream>>>(
      ctx, woutT, b_out, nullptr, nullptr, nullptr, out);
}

// Round 14
// 197.288 us; speedup vs baseline: 1.1885x; 1.1883x over previous
//
#include <hip/hip_runtime.h>
#include <stdint.h>

#define EMB 1024
#define SEQ 2048
#define NB 4
#define NH 16
#define HD 64
#define NGLOB 4
#define WIN 256
#define MTOT (NB*SEQ)   // 8192
#define NQKV (3*EMB)    // 3072

// per-partial: O^T bf16 [64][32] (4096 B) + m[32] f32 + l[32] f32 (256 B)
#define PART_U16 2176   // 4352 bytes in u16 units
#define NGJOBS 4160     // global wave-jobs (segments), band-indexed
#define NLJOBS 3072     // local wave-jobs

typedef __attribute__((ext_vector_type(8))) short bf16x8;
typedef __attribute__((ext_vector_type(4))) float f32x4;
typedef __attribute__((ext_vector_type(16))) float f32x16;
typedef unsigned short u16;
typedef unsigned int u32;

#define CL2 0.18033688011112042f  // 0.125 * log2(e)

#if __has_builtin(__builtin_amdgcn_exp2f)
#define EXP2(x) __builtin_amdgcn_exp2f(x)
#else
#define EXP2(x) exp2f(x)
#endif

__device__ __forceinline__ u16 f2bf(float f) {
  u32 u = __builtin_bit_cast(u32, f);
  u += 0x7fffu + ((u >> 16) & 1u);
  return (u16)(u >> 16);
}

__device__ __forceinline__ float bf2f(u16 v) {
  u32 u = (u32)v << 16;
  return __builtin_bit_cast(float, u);
}

// truncating pack of two f32 -> dword of two bf16 (lo = a, hi = b)
__device__ __forceinline__ u32 packtrunc(float a, float b) {
  u32 ua = __builtin_bit_cast(u32, a);
  u32 ub = __builtin_bit_cast(u32, b);
  return (ua >> 16) | (ub & 0xffff0000u);
}

// NOTE: __builtin_amdgcn_permlane32_swap is BANNED this session — produced
// wrong results twice (R2, R10; identical absmax signature). shfl_xor only.
// NOTE: XCD-swizzle on these GEMM grids is BANNED (R13): the natural gid%8
// mapping L2-blocks A (2 MB/XCD resident); chunked swizzle streams 16 MB
// through 4 MB L2 -> FETCH 181 MB, 65->111 us.

#define MFMA16(a, b, c) __builtin_amdgcn_mfma_f32_16x16x32_bf16(a, b, c, 0, 0, 0)
#define MFMA32(a, b, c) __builtin_amdgcn_mfma_f32_32x32x16_bf16(a, b, c, 0, 0, 0)
#define GLD16(g, l) __builtin_amdgcn_global_load_lds( \
    (const __attribute__((address_space(1))) void*)(g), \
    (__attribute__((address_space(3))) void*)(l), 16, 0, 0)

// ---------------- cast fp32 -> bf16 (vectorized) ----------------
__global__ void k_cast(const float* __restrict__ in, u16* __restrict__ out, int n4) {
  int i = blockIdx.x * blockDim.x + threadIdx.x;
  if (i >= n4) return;
  float4 f = ((const float4*)in)[i];
  ushort4 o;
  o.x = f2bf(f.x); o.y = f2bf(f.y); o.z = f2bf(f.z); o.w = f2bf(f.w);
  ((ushort4*)out)[i] = o;
}

// ---------------- transpose + cast: w[R][C] -> wt[C][R] bf16 ----------------
__global__ void k_transpose_cast(const float* __restrict__ w, u16* __restrict__ wt,
                                 int R, int C) {
  __shared__ float tile[32][33];
  int c0 = blockIdx.x * 32, r0 = blockIdx.y * 32;
  int tx = threadIdx.x, ty = threadIdx.y;  // 32 x 8
  #pragma unroll
  for (int j = 0; j < 32; j += 8)
    tile[ty + j][tx] = w[(size_t)(r0 + ty + j) * C + (c0 + tx)];
  __syncthreads();
  #pragma unroll
  for (int j = 0; j < 32; j += 8)
    wt[(size_t)(c0 + ty + j) * R + (r0 + tx)] = f2bf(tile[tx][ty + j]);
}

// ---------------- 128x128 bf16 MFMA GEMM, K=1024, B given transposed -------
// Plain 2D grid: blockIdx.x = m-tile (fastest -> XCD = m%8 -> A L2-blocked).
// EPI==0 epilogue: Q [bh][s][d], K [bh][s][d], Vf [bh][s>>4][d][s&15].
// EPI==1 epilogue: fp32 out + bias.
template <int EPI>
__global__ __launch_bounds__(256, 2) void k_gemm(
    const u16* __restrict__ A, const u16* __restrict__ Bt,
    const float* __restrict__ bias,
    u16* __restrict__ Qo, u16* __restrict__ Ko, u16* __restrict__ Vt,
    float* __restrict__ outp) {
  __shared__ __align__(16) u16 ldsA[128 * 64];
  __shared__ __align__(16) u16 ldsB[128 * 64];
  const int tid = threadIdx.x;
  const int w = tid >> 6, lane = tid & 63;
  const int wm = w >> 1, wn = w & 1;
  const int m0 = blockIdx.x * 128, n0 = blockIdx.y * 128;
  const int rq = lane & 15, g = lane >> 4;

  const int srow = lane >> 3;
  const int scol = ((lane & 7) ^ srow) << 3;

  f32x4 acc[4][4] = {};
  char* ldsAb = (char*)ldsA;
  char* ldsBb = (char*)ldsB;

  for (int k0 = 0; k0 < EMB; k0 += 64) {
    #pragma unroll
    for (int it = 0; it < 4; ++it) {
      int t = w * 4 + it;
      int row = t * 8 + srow;
      GLD16(A + (size_t)(m0 + row) * EMB + k0 + scol, ldsAb + t * 1024);
      GLD16(Bt + (size_t)(n0 + row) * EMB + k0 + scol, ldsBb + t * 1024);
    }
    __syncthreads();
    #pragma unroll
    for (int ks = 0; ks < 2; ++ks) {
      bf16x8 af[4], bfr[4];
      #pragma unroll
      for (int i = 0; i < 4; ++i) {
        int rowA = wm * 64 + i * 16 + rq;
        int off = (ks * 64 + (g << 4)) ^ ((rowA & 7) << 4);
        af[i] = *(const bf16x8*)(ldsAb + rowA * 128 + off);
        int rowB = wn * 64 + i * 16 + rq;
        int offb = (ks * 64 + (g << 4)) ^ ((rowB & 7) << 4);
        bfr[i] = *(const bf16x8*)(ldsBb + rowB * 128 + offb);
      }
      #pragma unroll
      for (int mi = 0; mi < 4; ++mi)
        #pragma unroll
        for (int ni = 0; ni < 4; ++ni)
          acc[mi][ni] = MFMA16(af[mi], bfr[ni], acc[mi][ni]);
    }
    __syncthreads();
  }

  #pragma unroll
  for (int ni = 0; ni < 4; ++ni) {
    int col = n0 + wn * 64 + ni * 16 + rq;
    float bv = bias[col];
    if (EPI == 0) {
      int part = col >> 10;
      int hh = (col & 1023) >> 6;
      int d = col & 63;
      #pragma unroll
      for (int mi = 0; mi < 4; ++mi) {
        #pragma unroll
        for (int i = 0; i < 4; ++i) {
          int m = m0 + wm * 64 + mi * 16 + g * 4 + i;
          int b = m >> 11, s = m & 2047;
          u16 val = f2bf(acc[mi][ni][i] + bv);
          size_t bh = (size_t)(b * NH + hh);
          if (part == 0)      Qo[(bh * SEQ + s) * HD + d] = val;
          else if (part == 1) Ko[(bh * SEQ + s) * HD + d] = val;
          else                Vt[((bh * 128 + (s >> 4)) * 64 + d) * 16 + (s & 15)] = val;
        }
      }
    } else {
      #pragma unroll
      for (int mi = 0; mi < 4; ++mi)
        #pragma unroll
        for (int i = 0; i < 4; ++i) {
          int m = m0 + wm * 64 + mi * 16 + g * 4 + i;
          outp[(size_t)m * EMB + col] = acc[mi][ni][i] + bv;
        }
    }
  }
}

// ---------------- flash attention pass 1: uniform wave-jobs (<=9 chunks) ----
// job j < NGJOBS: global-head SEGMENT (band-indexed). band>0 -> partial to
//   scratch; band==0 (nseg==1, full range) -> direct ctx write.
// job j >= NGJOBS: local-head task (<=9 chunks), direct ctx write.
__global__ __launch_bounds__(256, 4) void k_attn(
    const u16* __restrict__ Q, const u16* __restrict__ K,
    const u16* __restrict__ Vt, u16* __restrict__ ctx,
    u16* __restrict__ part) {
  const int w = threadIdx.x >> 6, lane = threadIdx.x & 63;
  const int l31 = lane & 31;
  const int hi = lane >> 5;
  const bool hib = hi != 0;
  const int hi8 = hi * 8, hi4 = hi * 4;

  const int j = blockIdx.x * 4 + w;         // wave-job id
  const bool isglob = j < NGJOBS;

  int bh, qt, cstart, clen, band = 0;
  if (isglob) {
    int rem = j, b = 0;
    while (b < 7 && rem >= 144 * (b + 1)) { rem -= 144 * (b + 1); ++b; }
    band = b;
    int nseg = b + 1;
    int qoff = (rem >> 4) / nseg;
    int r2 = rem - qoff * 16 * nseg;
    int seg = r2 >> 4, bg = r2 & 15;
    qt = 9 * b + qoff;
    bh = (bg >> 2) * 16 + (bg & 3);
    int L = qt + 1;
    int base = L / nseg, rm = L - base * nseg;
    clen = base + (seg < rm ? 1 : 0);
    cstart = seg * base + (seg < rm ? seg : rm);
  } else {
    int lidx = j - NGJOBS;                   // 0..3071
    int bl = lidx >> 6;
    bh = (bl / 12) * 16 + 4 + (bl % 12);
    qt = lidx & 63;
    int qb_ = qt * 32;
    int klo = (qb_ > WIN) ? qb_ - WIN : 0;
    cstart = klo >> 5;
    clen = qt + 1 - cstart;
  }

  const int qb = qt * 32;
  const int h = bh & 15;
  const int b_ = bh >> 4;
  const bool isloc = !isglob;

  const u16* Qp = Q + (size_t)bh * SEQ * HD;
  const u16* Kp = K + (size_t)bh * SEQ * HD;
  const u16* Vp = Vt + (size_t)bh * SEQ * HD;   // 16-key-blocked layout

  const int q = qb + l31;
  const float NINF = -__builtin_inff();

  bf16x8 qf[4];
  #pragma unroll
  for (int jj = 0; jj < 4; ++jj)
    qf[jj] = *(const bf16x8*)(Qp + (size_t)q * HD + jj * 16 + hi8);

  f32x16 oacc[2] = {};
  float m = NINF;
  float l = 0.f;

  int kc = cstart * 32;
  #pragma unroll 2
  for (int it = 0; it < clen; ++it, kc += 32) {
    bf16x8 kf0, kf1, kf2, kf3, vf[2][2];
    {
      const u16* Kr = Kp + (size_t)(kc + l31) * HD + hi8;
      kf0 = *(const bf16x8*)(Kr);
      kf1 = *(const bf16x8*)(Kr + 16);
      kf2 = *(const bf16x8*)(Kr + 32);
      kf3 = *(const bf16x8*)(Kr + 48);
      const u16* Vb = Vp + (size_t)(kc >> 4) * 1024 + hi8;
      #pragma unroll
      for (int dt = 0; dt < 2; ++dt)
        #pragma unroll
        for (int sl = 0; sl < 2; ++sl)
          vf[dt][sl] = *(const bf16x8*)(Vb + (sl * 64 + dt * 32 + l31) * 16);
    }

    f32x16 s0 = {}, s1 = {};
    s0 = MFMA32(kf0, qf[0], s0);
    s1 = MFMA32(kf2, qf[2], s1);
    s0 = MFMA32(kf1, qf[1], s0);
    s1 = MFMA32(kf3, qf[3], s1);

    const bool needs_mask = (kc == qb) || (isloc && (qb - kc > 225));
    float p[16];
    float cmax = NINF;
    if (needs_mask) {
      #pragma unroll
      for (int r = 0; r < 16; ++r) {
        int key = kc + hi4 + (r & 3) + 8 * (r >> 2);
        float v = s0[r] + s1[r];
        bool bad = (key > q) || (isloc && (q - key > WIN));
        p[r] = bad ? NINF : v;
        cmax = fmaxf(cmax, p[r]);
      }
    } else {
      #pragma unroll
      for (int r = 0; r < 16; ++r) {
        p[r] = s0[r] + s1[r];
        cmax = fmaxf(cmax, p[r]);
      }
    }
    cmax = fmaxf(cmax, __shfl_xor(cmax, 32));

    float muC;
    if (__any(cmax > m + 64.f)) {
      float mn = fmaxf(m, cmax);
      muC = (mn == NINF) ? 0.f : mn * CL2;
      float oldC = (m == NINF) ? muC : m * CL2;
      float f = EXP2(oldC - muC);
      m = mn;
      l *= f;
      #pragma unroll
      for (int dt = 0; dt < 2; ++dt)
        #pragma unroll
        for (int r = 0; r < 16; ++r)
          oacc[dt][r] *= f;
    } else {
      muC = (m == NINF) ? 0.f : m * CL2;
    }

    float psum = 0.f;
    #pragma unroll
    for (int r = 0; r < 16; ++r) {
      float e = EXP2(__builtin_fmaf(p[r], CL2, -muC));
      p[r] = e;
      psum += e;
    }
    psum += __shfl_xor(psum, 32);
    l += psum;

    union { u32 u[4]; bf16x8 v; } pbf[2];
    #pragma unroll
    for (int sl = 0; sl < 2; ++sl) {
      int s8 = sl * 8;
      u32 X0 = packtrunc(p[s8 + 0], p[s8 + 1]);
      u32 X1 = packtrunc(p[s8 + 2], p[s8 + 3]);
      u32 X2 = packtrunc(p[s8 + 4], p[s8 + 5]);
      u32 X3 = packtrunc(p[s8 + 6], p[s8 + 7]);
      u32 oX0 = (u32)__shfl_xor((int)X0, 32);
      u32 oX1 = (u32)__shfl_xor((int)X1, 32);
      u32 oX2 = (u32)__shfl_xor((int)X2, 32);
      u32 oX3 = (u32)__shfl_xor((int)X3, 32);
      pbf[sl].u[0] = hib ? oX2 : X0;
      pbf[sl].u[1] = hib ? oX3 : X1;
      pbf[sl].u[2] = hib ? X2 : oX0;
      pbf[sl].u[3] = hib ? X3 : oX1;
    }

    #pragma unroll
    for (int dt = 0; dt < 2; ++dt)
      #pragma unroll
      for (int sl = 0; sl < 2; ++sl)
        oacc[dt] = MFMA32(vf[dt][sl], pbf[sl].v, oacc[dt]);
  }

  if (isglob && band != 0) {
    // store wave-private partial: O^T bf16 [64][32] + m,l f32 at slot j
    u16* PB = part + (size_t)j * PART_U16;
    #pragma unroll
    for (int dt = 0; dt < 2; ++dt)
      #pragma unroll
      for (int r = 0; r < 16; ++r) {
        int d = dt * 32 + hi4 + (r & 3) + 8 * (r >> 2);
        PB[d * 32 + l31] = f2bf(oacc[dt][r]);
      }
    float* PF = (float*)(PB + 2048);
    if (hi == 0) { PF[l31] = m; PF[32 + l31] = l; }
  } else {
    // direct write (locals, and band-0 globals which cover the full range)
    float linv = 1.f / l;
    #pragma unroll
    for (int dt = 0; dt < 2; ++dt) {
      #pragma unroll
      for (int r = 0; r < 16; ++r) {
        int d = dt * 32 + hi4 + (r & 3) + 8 * (r >> 2);
        int e = h * HD + d;
        ctx[(size_t)(b_ * SEQ + q) * EMB + e] = f2bf(oacc[dt][r] * linv);
      }
    }
  }
}

// ---------------- flash attention pass 2: merge nseg partials per task ----
// LDS-staged: O-partials copied coalesced, read transposed via padded rows.
__global__ __launch_bounds__(256, 4) void k_merge(
    const u16* __restrict__ part, u16* __restrict__ ctx) {
  const int t = blockIdx.x;                  // 0..1023: (qt, bg)
  const int bg = t & 15;
  const int qt = t >> 4;
  const int band = qt / 9;                   // 0..7
  const int nseg = band + 1;
  if (nseg == 1) return;                     // pass 1 wrote ctx directly
  const int jbase = 72 * band * (band + 1) + (qt - 9 * band) * 16 * nseg + bg;
  const int bh = (bg >> 2) * 16 + (bg & 3);
  const int qb = qt * 32;
  const int h = bh & 15;
  const int bb = bh >> 4;

  __shared__ u16 ob[64][34];                 // padded: 2-way max (free)
  __shared__ float fml[8][64];               // [seg][m[32] | l[32]]

  const int tid = threadIdx.x;
  for (int e = tid; e < nseg * 64; e += 256) {
    int s = e >> 6, k = e & 63;
    fml[s][k] = ((const float*)(part + (size_t)(jbase + s * 16) * PART_U16 + 2048))[k];
  }
  __syncthreads();

  const int dd = tid & 63;
  const int qg = tid >> 6;                   // 0..3
  float M[8], Lsum[8], val[8];
  #pragma unroll
  for (int i = 0; i < 8; ++i) {
    int qq = qg * 8 + i;
    float mx = fml[0][qq];
    for (int s = 1; s < nseg; ++s) mx = fmaxf(mx, fml[s][qq]);
    M[i] = mx; Lsum[i] = 0.f; val[i] = 0.f;
  }

  for (int s = 0; s < nseg; ++s) {
    __syncthreads();
    const u32* src = (const u32*)(part + (size_t)(jbase + s * 16) * PART_U16);
    #pragma unroll
    for (int c = 0; c < 4; ++c) {
      int wd = tid * 4 + c;                  // 0..1023 words of the 4KB O-part
      *(u32*)&ob[wd >> 4][(wd & 15) * 2] = src[wd];
    }
    __syncthreads();
    #pragma unroll
    for (int i = 0; i < 8; ++i) {
      int qq = qg * 8 + i;
      float wgt = EXP2((fml[s][qq] - M[i]) * CL2);
      Lsum[i] += wgt * fml[s][32 + qq];
      val[i] += wgt * bf2f(ob[dd][qq]);
    }
  }

  #pragma unroll
  for (int i = 0; i < 8; ++i) {
    int qq = qg * 8 + i;
    ctx[(size_t)(bb * SEQ + (qb + qq)) * EMB + h * HD + dd] = f2bf(val[i] / Lsum[i]);
  }
}

extern "C" void kernel_launch(void* const* d_in, const int* in_sizes, int n_in,
                              void* d_out, int out_size, void* d_ws, size_t ws_size,
                              hipStream_t stream) {
  const float* x     = (const float*)d_in[0];
  const float* w_qkv = (const float*)d_in[1];
  const float* b_qkv = (const float*)d_in[2];
  const float* w_out = (const float*)d_in[3];
  const float* b_out = (const float*)d_in[4];
  float* out = (float*)d_out;

  char* ws = (char*)d_ws;
  u16* xb    = (u16*)(ws);                   // 16 MiB (dead after k_gemm<0>)
  u16* wqkvT = (u16*)(ws + (16ull << 20));   // 6 MiB  (dead after k_gemm<0>)
  u16* woutT = (u16*)(ws + (22ull << 20));   // 2 MiB
  u16* Qb    = (u16*)(ws + (24ull << 20));   // 16 MiB
  u16* Kb    = (u16*)(ws + (40ull << 20));   // 16 MiB
  u16* Vt    = (u16*)(ws + (56ull << 20));   // 16 MiB (16-key-blocked layout)
  u16* ctx   = (u16*)(ws + (72ull << 20));   // 16 MiB
  u16* part  = xb;                           // 18.1 MiB partials (xb+wqkvT)

  k_cast<<<(MTOT * EMB / 4) / 256, 256, 0, stream>>>(x, xb, MTOT * EMB / 4);
  dim3 tb(32, 8);
  k_transpose_cast<<<dim3(NQKV / 32, EMB / 32), tb, 0, stream>>>(w_qkv, wqkvT, EMB, NQKV);
  k_transpose_cast<<<dim3(EMB / 32, EMB / 32), tb, 0, stream>>>(w_out, woutT, EMB, EMB);

  k_gemm<0><<<dim3(MTOT / 128, NQKV / 128), 256, 0, stream>>>(
      xb, wqkvT, b_qkv, Qb, Kb, Vt, nullptr);

  k_attn<<<dim3((NGJOBS + NLJOBS) / 4), 256, 0, stream>>>(Qb, Kb, Vt, ctx, part);
  k_merge<<<dim3(1024), 256, 0, stream>>>(part, ctx);

  k_gemm<1><<<dim3(MTOT / 128, EMB / 128), 256, 0, stream>>>(
      ctx, woutT, b_out, nullptr, nullptr, nullptr, out);
}

// Round 15
// 197.119 us; speedup vs baseline: 1.1895x; 1.0009x over previous
//
#include <hip/hip_runtime.h>
#include <stdint.h>

#define EMB 1024
#define SEQ 2048
#define NB 4
#define NH 16
#define HD 64
#define NGLOB 4
#define WIN 256
#define MTOT (NB*SEQ)   // 8192
#define NQKV (3*EMB)    // 3072

// per-partial: O^T bf16 [64][32] (4096 B) + m[32] f32 + l[32] f32 (256 B)
#define PART_U16 2176   // 4352 bytes in u16 units
// jobs per global bg: sum_b 9*(b+1) for b=0..6, +8 for band7 (qt=63) = 260
#define JOBS_PER_BG 260

typedef __attribute__((ext_vector_type(8))) short bf16x8;
typedef __attribute__((ext_vector_type(4))) float f32x4;
typedef __attribute__((ext_vector_type(16))) float f32x16;
typedef unsigned short u16;
typedef unsigned int u32;

#define CL2 0.18033688011112042f  // 0.125 * log2(e)

#if __has_builtin(__builtin_amdgcn_exp2f)
#define EXP2(x) __builtin_amdgcn_exp2f(x)
#else
#define EXP2(x) exp2f(x)
#endif

__device__ __forceinline__ u16 f2bf(float f) {
  u32 u = __builtin_bit_cast(u32, f);
  u += 0x7fffu + ((u >> 16) & 1u);
  return (u16)(u >> 16);
}

__device__ __forceinline__ float bf2f(u16 v) {
  u32 u = (u32)v << 16;
  return __builtin_bit_cast(float, u);
}

// truncating pack of two f32 -> dword of two bf16 (lo = a, hi = b)
__device__ __forceinline__ u32 packtrunc(float a, float b) {
  u32 ua = __builtin_bit_cast(u32, a);
  u32 ub = __builtin_bit_cast(u32, b);
  return (ua >> 16) | (ub & 0xffff0000u);
}

// NOTE: __builtin_amdgcn_permlane32_swap is BANNED this session (R2, R10).
// NOTE: XCD-swizzle on the GEMM grids is BANNED (R13): natural gid%8 already
// L2-blocks A. For k_attn we EXPLOIT gid%8==XCD to cluster jobs by head.

#define MFMA16(a, b, c) __builtin_amdgcn_mfma_f32_16x16x32_bf16(a, b, c, 0, 0, 0)
#define MFMA32(a, b, c) __builtin_amdgcn_mfma_f32_32x32x16_bf16(a, b, c, 0, 0, 0)
#define GLD16(g, l) __builtin_amdgcn_global_load_lds( \
    (const __attribute__((address_space(1))) void*)(g), \
    (__attribute__((address_space(3))) void*)(l), 16, 0, 0)

// ---------------- cast fp32 -> bf16 (vectorized) ----------------
__global__ void k_cast(const float* __restrict__ in, u16* __restrict__ out, int n4) {
  int i = blockIdx.x * blockDim.x + threadIdx.x;
  if (i >= n4) return;
  float4 f = ((const float4*)in)[i];
  ushort4 o;
  o.x = f2bf(f.x); o.y = f2bf(f.y); o.z = f2bf(f.z); o.w = f2bf(f.w);
  ((ushort4*)out)[i] = o;
}

// ---------------- transpose + cast: w[R][C] -> wt[C][R] bf16 ----------------
__global__ void k_transpose_cast(const float* __restrict__ w, u16* __restrict__ wt,
                                 int R, int C) {
  __shared__ float tile[32][33];
  int c0 = blockIdx.x * 32, r0 = blockIdx.y * 32;
  int tx = threadIdx.x, ty = threadIdx.y;  // 32 x 8
  #pragma unroll
  for (int j = 0; j < 32; j += 8)
    tile[ty + j][tx] = w[(size_t)(r0 + ty + j) * C + (c0 + tx)];
  __syncthreads();
  #pragma unroll
  for (int j = 0; j < 32; j += 8)
    wt[(size_t)(c0 + ty + j) * R + (r0 + tx)] = f2bf(tile[tx][ty + j]);
}

// ---------------- 128x128 bf16 MFMA GEMM, K=1024, B given transposed -------
template <int EPI>
__global__ __launch_bounds__(256, 2) void k_gemm(
    const u16* __restrict__ A, const u16* __restrict__ Bt,
    const float* __restrict__ bias,
    u16* __restrict__ Qo, u16* __restrict__ Ko, u16* __restrict__ Vt,
    float* __restrict__ outp) {
  __shared__ __align__(16) u16 ldsA[128 * 64];
  __shared__ __align__(16) u16 ldsB[128 * 64];
  const int tid = threadIdx.x;
  const int w = tid >> 6, lane = tid & 63;
  const int wm = w >> 1, wn = w & 1;
  const int m0 = blockIdx.x * 128, n0 = blockIdx.y * 128;
  const int rq = lane & 15, g = lane >> 4;

  const int srow = lane >> 3;
  const int scol = ((lane & 7) ^ srow) << 3;

  f32x4 acc[4][4] = {};
  char* ldsAb = (char*)ldsA;
  char* ldsBb = (char*)ldsB;

  for (int k0 = 0; k0 < EMB; k0 += 64) {
    #pragma unroll
    for (int it = 0; it < 4; ++it) {
      int t = w * 4 + it;
      int row = t * 8 + srow;
      GLD16(A + (size_t)(m0 + row) * EMB + k0 + scol, ldsAb + t * 1024);
      GLD16(Bt + (size_t)(n0 + row) * EMB + k0 + scol, ldsBb + t * 1024);
    }
    __syncthreads();
    #pragma unroll
    for (int ks = 0; ks < 2; ++ks) {
      bf16x8 af[4], bfr[4];
      #pragma unroll
      for (int i = 0; i < 4; ++i) {
        int rowA = wm * 64 + i * 16 + rq;
        int off = (ks * 64 + (g << 4)) ^ ((rowA & 7) << 4);
        af[i] = *(const bf16x8*)(ldsAb + rowA * 128 + off);
        int rowB = wn * 64 + i * 16 + rq;
        int offb = (ks * 64 + (g << 4)) ^ ((rowB & 7) << 4);
        bfr[i] = *(const bf16x8*)(ldsBb + rowB * 128 + offb);
      }
      #pragma unroll
      for (int mi = 0; mi < 4; ++mi)
        #pragma unroll
        for (int ni = 0; ni < 4; ++ni)
          acc[mi][ni] = MFMA16(af[mi], bfr[ni], acc[mi][ni]);
    }
    __syncthreads();
  }

  #pragma unroll
  for (int ni = 0; ni < 4; ++ni) {
    int col = n0 + wn * 64 + ni * 16 + rq;
    float bv = bias[col];
    if (EPI == 0) {
      int part = col >> 10;
      int hh = (col & 1023) >> 6;
      int d = col & 63;
      #pragma unroll
      for (int mi = 0; mi < 4; ++mi) {
        #pragma unroll
        for (int i = 0; i < 4; ++i) {
          int m = m0 + wm * 64 + mi * 16 + g * 4 + i;
          int b = m >> 11, s = m & 2047;
          u16 val = f2bf(acc[mi][ni][i] + bv);
          size_t bh = (size_t)(b * NH + hh);
          if (part == 0)      Qo[(bh * SEQ + s) * HD + d] = val;
          else if (part == 1) Ko[(bh * SEQ + s) * HD + d] = val;
          else                Vt[((bh * 128 + (s >> 4)) * 64 + d) * 16 + (s & 15)] = val;
        }
      }
    } else {
      #pragma unroll
      for (int mi = 0; mi < 4; ++mi)
        #pragma unroll
        for (int i = 0; i < 4; ++i) {
          int m = m0 + wm * 64 + mi * 16 + g * 4 + i;
          outp[(size_t)m * EMB + col] = acc[mi][ni][i] + bv;
        }
    }
  }
}

// ---------------- flash attention pass 1: XCD-clustered wave-jobs ----------
// gid = j*8 + x  (x = XCD, empirically gid%8). XCD x owns:
//   global bg in {2x, 2x+1}  (130 blocks: jobs bg-major, triangular band order
//     B(b)=9*b*(b+1)/2; job r -> band b, qoff=rb/(b+1), seg=rb%(b+1))
//   local  bl in {6x .. 6x+5} (96 blocks)
// K/V hot set per XCD = 8 heads x 512 KB = 4 MB = one L2.
__global__ __launch_bounds__(256, 4) void k_attn(
    const u16* __restrict__ Q, const u16* __restrict__ K,
    const u16* __restrict__ Vt, u16* __restrict__ ctx,
    u16* __restrict__ part) {
  const int w = threadIdx.x >> 6, lane = threadIdx.x & 63;
  const int l31 = lane & 31;
  const int hi = lane >> 5;
  const bool hib = hi != 0;
  const int hi8 = hi * 8, hi4 = hi * 4;

  const int gid = blockIdx.x;
  const int x = gid & 7;                    // XCD
  const int jb = gid >> 3;                  // 0..225 within XCD
  const bool isglob = jb < 130;

  int bh, qt, cstart, clen, band = 0, slot = 0;
  if (isglob) {
    int pk = jb * 4 + w;                    // 0..519
    int bg = 2 * x + (pk >= JOBS_PER_BG);
    int r = (pk >= JOBS_PER_BG) ? pk - JOBS_PER_BG : pk;
    int b = 0;
    while (b < 7 && r >= 9 * (b + 1) * (b + 2) / 2) ++b;
    band = b;
    int rb = r - 9 * b * (b + 1) / 2;
    int nseg = b + 1;
    if (b == 7) nseg = 8;
    int qoff = rb / nseg;
    int seg = rb - qoff * nseg;
    qt = 9 * b + qoff;
    bh = (bg >> 2) * 16 + (bg & 3);
    slot = bg * JOBS_PER_BG + r;
    int L = qt + 1;
    int base = L / nseg, rm = L - base * nseg;
    clen = base + (seg < rm ? 1 : 0);
    cstart = seg * base + (seg < rm ? seg : rm);
  } else {
    int lj = (jb - 130) * 4 + w;            // 0..383
    int bls = lj >> 6;                      // 0..5
    int bl = 6 * x + bls;                   // 0..47
    qt = lj & 63;
    bh = (bl / 12) * 16 + 4 + (bl % 12);
    int qb_ = qt * 32;
    int klo = (qb_ > WIN) ? qb_ - WIN : 0;
    cstart = klo >> 5;
    clen = qt + 1 - cstart;
  }

  const int qb = qt * 32;
  const int h = bh & 15;
  const int b_ = bh >> 4;
  const bool isloc = !isglob;

  const u16* Qp = Q + (size_t)bh * SEQ * HD;
  const u16* Kp = K + (size_t)bh * SEQ * HD;
  const u16* Vp = Vt + (size_t)bh * SEQ * HD;   // 16-key-blocked layout

  const int q = qb + l31;
  const float NINF = -__builtin_inff();

  bf16x8 qf[4];
  #pragma unroll
  for (int jj = 0; jj < 4; ++jj)
    qf[jj] = *(const bf16x8*)(Qp + (size_t)q * HD + jj * 16 + hi8);

  f32x16 oacc[2] = {};
  float m = NINF;
  float l = 0.f;

  int kc = cstart * 32;
  #pragma unroll 2
  for (int it = 0; it < clen; ++it, kc += 32) {
    bf16x8 kf0, kf1, kf2, kf3, vf[2][2];
    {
      const u16* Kr = Kp + (size_t)(kc + l31) * HD + hi8;
      kf0 = *(const bf16x8*)(Kr);
      kf1 = *(const bf16x8*)(Kr + 16);
      kf2 = *(const bf16x8*)(Kr + 32);
      kf3 = *(const bf16x8*)(Kr + 48);
      const u16* Vb = Vp + (size_t)(kc >> 4) * 1024 + hi8;
      #pragma unroll
      for (int dt = 0; dt < 2; ++dt)
        #pragma unroll
        for (int sl = 0; sl < 2; ++sl)
          vf[dt][sl] = *(const bf16x8*)(Vb + (sl * 64 + dt * 32 + l31) * 16);
    }

    f32x16 s0 = {}, s1 = {};
    s0 = MFMA32(kf0, qf[0], s0);
    s1 = MFMA32(kf2, qf[2], s1);
    s0 = MFMA32(kf1, qf[1], s0);
    s1 = MFMA32(kf3, qf[3], s1);

    const bool needs_mask = (kc == qb) || (isloc && (qb - kc > 225));
    float p[16];
    float cmax = NINF;
    if (needs_mask) {
      #pragma unroll
      for (int r = 0; r < 16; ++r) {
        int key = kc + hi4 + (r & 3) + 8 * (r >> 2);
        float v = s0[r] + s1[r];
        bool bad = (key > q) || (isloc && (q - key > WIN));
        p[r] = bad ? NINF : v;
        cmax = fmaxf(cmax, p[r]);
      }
    } else {
      #pragma unroll
      for (int r = 0; r < 16; ++r) {
        p[r] = s0[r] + s1[r];
        cmax = fmaxf(cmax, p[r]);
      }
    }
    cmax = fmaxf(cmax, __shfl_xor(cmax, 32));

    float muC;
    if (__any(cmax > m + 64.f)) {
      float mn = fmaxf(m, cmax);
      muC = (mn == NINF) ? 0.f : mn * CL2;
      float oldC = (m == NINF) ? muC : m * CL2;
      float f = EXP2(oldC - muC);
      m = mn;
      l *= f;
      #pragma unroll
      for (int dt = 0; dt < 2; ++dt)
        #pragma unroll
        for (int r = 0; r < 16; ++r)
          oacc[dt][r] *= f;
    } else {
      muC = (m == NINF) ? 0.f : m * CL2;
    }

    float psum = 0.f;
    #pragma unroll
    for (int r = 0; r < 16; ++r) {
      float e = EXP2(__builtin_fmaf(p[r], CL2, -muC));
      p[r] = e;
      psum += e;
    }
    psum += __shfl_xor(psum, 32);
    l += psum;

    union { u32 u[4]; bf16x8 v; } pbf[2];
    #pragma unroll
    for (int sl = 0; sl < 2; ++sl) {
      int s8 = sl * 8;
      u32 X0 = packtrunc(p[s8 + 0], p[s8 + 1]);
      u32 X1 = packtrunc(p[s8 + 2], p[s8 + 3]);
      u32 X2 = packtrunc(p[s8 + 4], p[s8 + 5]);
      u32 X3 = packtrunc(p[s8 + 6], p[s8 + 7]);
      u32 oX0 = (u32)__shfl_xor((int)X0, 32);
      u32 oX1 = (u32)__shfl_xor((int)X1, 32);
      u32 oX2 = (u32)__shfl_xor((int)X2, 32);
      u32 oX3 = (u32)__shfl_xor((int)X3, 32);
      pbf[sl].u[0] = hib ? oX2 : X0;
      pbf[sl].u[1] = hib ? oX3 : X1;
      pbf[sl].u[2] = hib ? X2 : oX0;
      pbf[sl].u[3] = hib ? X3 : oX1;
    }

    #pragma unroll
    for (int dt = 0; dt < 2; ++dt)
      #pragma unroll
      for (int sl = 0; sl < 2; ++sl)
        oacc[dt] = MFMA32(vf[dt][sl], pbf[sl].v, oacc[dt]);
  }

  if (isglob && band != 0) {
    // store wave-private partial: O^T bf16 [64][32] + m,l f32 at slot
    u16* PB = part + (size_t)slot * PART_U16;
    #pragma unroll
    for (int dt = 0; dt < 2; ++dt)
      #pragma unroll
      for (int r = 0; r < 16; ++r) {
        int d = dt * 32 + hi4 + (r & 3) + 8 * (r >> 2);
        PB[d * 32 + l31] = f2bf(oacc[dt][r]);
      }
    float* PF = (float*)(PB + 2048);
    if (hi == 0) { PF[l31] = m; PF[32 + l31] = l; }
  } else {
    // direct write (locals, and band-0 globals which cover the full range)
    float linv = 1.f / l;
    #pragma unroll
    for (int dt = 0; dt < 2; ++dt) {
      #pragma unroll
      for (int r = 0; r < 16; ++r) {
        int d = dt * 32 + hi4 + (r & 3) + 8 * (r >> 2);
        int e = h * HD + d;
        ctx[(size_t)(b_ * SEQ + q) * EMB + e] = f2bf(oacc[dt][r] * linv);
      }
    }
  }
}

// ---------------- flash attention pass 2: merge nseg partials per task ----
// Slots per task are now CONSECUTIVE: jbase = bg*260 + B(band) + qoff*nseg.
__global__ __launch_bounds__(256, 4) void k_merge(
    const u16* __restrict__ part, u16* __restrict__ ctx) {
  const int t = blockIdx.x;                  // 0..1023: (qt, bg)
  const int bg = t & 15;
  const int qt = t >> 4;
  const int band = qt / 9;                   // 0..7 (qt=63 -> 7)
  const int nseg = band + 1;
  if (nseg == 1) return;                     // pass 1 wrote ctx directly
  const int jbase = bg * JOBS_PER_BG + 9 * band * (band + 1) / 2
                    + (qt - 9 * band) * nseg;
  const int bh = (bg >> 2) * 16 + (bg & 3);
  const int qb = qt * 32;
  const int h = bh & 15;
  const int bb = bh >> 4;

  __shared__ u16 ob[64][34];                 // padded: 2-way max (free)
  __shared__ float fml[8][64];               // [seg][m[32] | l[32]]

  const int tid = threadIdx.x;
  for (int e = tid; e < nseg * 64; e += 256) {
    int s = e >> 6, k = e & 63;
    fml[s][k] = ((const float*)(part + (size_t)(jbase + s) * PART_U16 + 2048))[k];
  }
  __syncthreads();

  const int dd = tid & 63;
  const int qg = tid >> 6;                   // 0..3
  float M[8], Lsum[8], val[8];
  #pragma unroll
  for (int i = 0; i < 8; ++i) {
    int qq = qg * 8 + i;
    float mx = fml[0][qq];
    for (int s = 1; s < nseg; ++s) mx = fmaxf(mx, fml[s][qq]);
    M[i] = mx; Lsum[i] = 0.f; val[i] = 0.f;
  }

  for (int s = 0; s < nseg; ++s) {
    __syncthreads();
    const u32* src = (const u32*)(part + (size_t)(jbase + s) * PART_U16);
    #pragma unroll
    for (int c = 0; c < 4; ++c) {
      int wd = tid * 4 + c;                  // 0..1023 words of the 4KB O-part
      *(u32*)&ob[wd >> 4][(wd & 15) * 2] = src[wd];
    }
    __syncthreads();
    #pragma unroll
    for (int i = 0; i < 8; ++i) {
      int qq = qg * 8 + i;
      float wgt = EXP2((fml[s][qq] - M[i]) * CL2);
      Lsum[i] += wgt * fml[s][32 + qq];
      val[i] += wgt * bf2f(ob[dd][qq]);
    }
  }

  #pragma unroll
  for (int i = 0; i < 8; ++i) {
    int qq = qg * 8 + i;
    ctx[(size_t)(bb * SEQ + (qb + qq)) * EMB + h * HD + dd] = f2bf(val[i] / Lsum[i]);
  }
}

extern "C" void kernel_launch(void* const* d_in, const int* in_sizes, int n_in,
                              void* d_out, int out_size, void* d_ws, size_t ws_size,
                              hipStream_t stream) {
  const float* x     = (const float*)d_in[0];
  const float* w_qkv = (const float*)d_in[1];
  const float* b_qkv = (const float*)d_in[2];
  const float* w_out = (const float*)d_in[3];
  const float* b_out = (const float*)d_in[4];
  float* out = (float*)d_out;

  char* ws = (char*)d_ws;
  u16* xb    = (u16*)(ws);                   // 16 MiB (dead after k_gemm<0>)
  u16* wqkvT = (u16*)(ws + (16ull << 20));   // 6 MiB  (dead after k_gemm<0>)
  u16* woutT = (u16*)(ws + (22ull << 20));   // 2 MiB
  u16* Qb    = (u16*)(ws + (24ull << 20));   // 16 MiB
  u16* Kb    = (u16*)(ws + (40ull << 20));   // 16 MiB
  u16* Vt    = (u16*)(ws + (56ull << 20));   // 16 MiB (16-key-blocked layout)
  u16* ctx   = (u16*)(ws + (72ull << 20));   // 16 MiB
  u16* part  = xb;                           // 18.1 MiB partials (xb+wqkvT)

  k_cast<<<(MTOT * EMB / 4) / 256, 256, 0, stream>>>(x, xb, MTOT * EMB / 4);
  dim3 tb(32, 8);
  k_transpose_cast<<<dim3(NQKV / 32, EMB / 32), tb, 0, stream>>>(w_qkv, wqkvT, EMB, NQKV);
  k_transpose_cast<<<dim3(EMB / 32, EMB / 32), tb, 0, stream>>>(w_out, woutT, EMB, EMB);

  k_gemm<0><<<dim3(MTOT / 128, NQKV / 128), 256, 0, stream>>>(
      xb, wqkvT, b_qkv, Qb, Kb, Vt, nullptr);

  k_attn<<<dim3(226 * 8), 256, 0, stream>>>(Qb, Kb, Vt, ctx, part);
  k_merge<<<dim3(1024), 256, 0, stream>>>(part, ctx);

  k_gemm<1><<<dim3(MTOT / 128, EMB / 128), 256, 0, stream>>>(
      ctx, woutT, b_out, nullptr, nullptr, nullptr, out);
}